// Round 3
// baseline (357.516 us; speedup 1.0000x reference)
//
#include <hip/hip_runtime.h>

typedef unsigned short u16;
typedef __attribute__((ext_vector_type(8))) short bf16x8;   // 8 bf16 = 4 VGPR
typedef __attribute__((ext_vector_type(4))) float f32x4;

#define BATCH 16
#define SEQ   2048
#define EMBD  512
#define NOUT  8
#define QB    64
#define KVB   64
#define NT    (SEQ/KVB)      // 32 KV tiles

#define GLOBAL_AS __attribute__((address_space(1)))
#define LDS_AS    __attribute__((address_space(3)))

__device__ __forceinline__ u16 f2bf(float f){          // f32 -> bf16 RNE
  unsigned u = __float_as_uint(f);
  u += 0x7fffu + ((u >> 16) & 1u);
  return (u16)(u >> 16);
}

__device__ __forceinline__ void gload_lds16(const void* g, void* l){
  __builtin_amdgcn_global_load_lds((const GLOBAL_AS unsigned int*)g,
                                   (LDS_AS unsigned int*)l, 16, 0, 0);
}

// ---------------------------------------------------------------------------
// Kernel 0: E[b*SEQ+n][e] = bf16(table[x[b,n]][e]); padding_idx==0 -> zeros.
// ---------------------------------------------------------------------------
__global__ __launch_bounds__(512) void k_embed(const int* __restrict__ x,
                                               const float* __restrict__ tab,
                                               u16* __restrict__ E){
  int r = blockIdx.x * 8 + (threadIdx.x >> 6);   // 0..32767
  int l = threadIdx.x & 63;
  int idx = x[r];
  float4 a = make_float4(0.f,0.f,0.f,0.f), c = a;
  if (idx != 0){
    const float4* src = (const float4*)(tab + (size_t)idx * EMBD);
    a = src[l*2]; c = src[l*2+1];
  }
  bf16x8 v;
  v[0]=f2bf(a.x); v[1]=f2bf(a.y); v[2]=f2bf(a.z); v[3]=f2bf(a.w);
  v[4]=f2bf(c.x); v[5]=f2bf(c.y); v[6]=f2bf(c.z); v[7]=f2bf(c.w);
  *(bf16x8*)(E + (size_t)r * EMBD + l*8) = v;
}

// ---------------------------------------------------------------------------
// Kernel 0b: Et[b][e][tok] = E[b][tok][e]  (per-batch 512 x 2048 transpose)
// 64x64 LDS-tiled. 4096 blocks x 256 threads.
// ---------------------------------------------------------------------------
__global__ __launch_bounds__(256) void k_transpose(const u16* __restrict__ E,
                                                   u16* __restrict__ Et){
  __shared__ u16 Lt[64][72];
  const int bi = blockIdx.x;
  const int b = bi >> 8, rem = bi & 255, tt = rem >> 3, et = rem & 7;
  const int tok0 = tt * 64, e0 = et * 64;
  const int t = threadIdx.x, r = t >> 2, cq = t & 3;
  const u16* src = E + ((size_t)b*SEQ + tok0 + r) * EMBD + e0 + cq*16;
  *(bf16x8*)&Lt[r][cq*16]     = *(const bf16x8*)(src);
  *(bf16x8*)&Lt[r][cq*16 + 8] = *(const bf16x8*)(src + 8);
  __syncthreads();
  bf16x8 o0, o1;
  #pragma unroll
  for (int i = 0; i < 8; i++){
    o0[i] = Lt[cq*16 + i][r];
    o1[i] = Lt[cq*16 + 8 + i][r];
  }
  u16* dst = Et + ((size_t)b*EMBD + e0 + r) * SEQ + tok0 + cq*16;
  *(bf16x8*)(dst)     = o0;
  *(bf16x8*)(dst + 8) = o1;
}

// ---------------------------------------------------------------------------
// Kernel 1 (Et path): flash attention + per-Q-tile column max.
// 512 thr (8 waves) per (batch, 64-row Q tile). KVB=64.
// - K: double-buffered LDS via global_load_lds, src pre-swizzled
//   (16B-chunk ^ row&7) -> conflict-free ds_read_b128 kb fragments.
// - S split: wave w = (qg=w&1 -> 32 q rows, kg=w>>1 -> 16 tokens): only 2
//   waves share each kb fragment (halves kb LDS traffic vs 4).
// - V: B-fragments read directly from global Et (L2-resident, XCD-affine).
// - 2 barriers per tile. stage(t+1) issued at tile top (drained at B1).
// ---------------------------------------------------------------------------
__global__ __launch_bounds__(512, 2) void k_attn_et(const u16* __restrict__ E,
                                                    const u16* __restrict__ Et,
                                                    float* __restrict__ part){
  __shared__ u16   Klds[2][KVB * EMBD];  // 2 x 64 KB
  __shared__ float Sbuf[QB][68];         // 17.4 KB
  __shared__ u16   Ps[QB][72];           // 9.2 KB
  __shared__ float m_lds[QB], l_lds[QB], a_lds[QB];

  const int tid = threadIdx.x;
  const int w   = tid >> 6;              // wave 0..7
  const int l   = tid & 63;
  const int l15 = l & 15, lg = l >> 4;

  // XCD-affine decode: batch b's 32 q-tiles land on XCD (b&7).
  const int blk  = blockIdx.x;
  const int xcd  = blk & 7;
  const int slot = blk >> 3;             // 0..63
  const int b    = xcd + 8 * (slot >> 5);
  const int qt   = slot & 31;
  const size_t ebase  = (size_t)b * SEQ * EMBD;
  const size_t etbase = (size_t)b * EMBD * SEQ;

  const int qg = w & 1;                  // q block: rows qg*32..+32
  const int kg = w >> 2 ? (w >> 1) : (w >> 1);  // k block 0..3
  const int kgi = w >> 1;                // k block: tokens kgi*16..+16
  (void)kg;

  // ---- Q fragments in registers: rows [qt*64+qg*32, +32), full D ----
  bf16x8 qf[2][16];
  #pragma unroll
  for (int ip = 0; ip < 2; ip++){
    const u16* qp = E + ebase
        + (size_t)(qt*QB + qg*32 + ip*16 + l15) * EMBD + lg*8;
    #pragma unroll
    for (int es = 0; es < 16; es++) qf[ip][es] = *(const bf16x8*)(qp + es*32);
  }

  f32x4 acc[4][4];                       // O[ip*16+lg*4+rr][w*64+jp*16+l15]
  #pragma unroll
  for (int ip = 0; ip < 4; ip++)
    #pragma unroll
    for (int jp = 0; jp < 4; jp++) acc[ip][jp] = (f32x4){0.f,0.f,0.f,0.f};

  if (tid < QB){ m_lds[tid] = -INFINITY; l_lds[tid] = 0.f; }

  // stage(tile) into Klds[bi]: thread -> 16B chunks o = tid + i*512
  // row = w + i*8, chunk_st = l, logical chunk = l ^ (row&7)
  #define STAGE(bi_, tile_)                                                  \
    { const int kk0 = (tile_) * KVB;                                         \
      _Pragma("unroll")                                                      \
      for (int i = 0; i < 8; i++){                                           \
        const int row = w + i*8;                                             \
        const u16* src = E + ebase + (size_t)(kk0 + row) * EMBD              \
                           + ((l ^ (row & 7)) * 8);                          \
        gload_lds16(src, &Klds[bi_][row * EMBD + l * 8]);                    \
      } }

  STAGE(0, 0)
  __syncthreads();                       // drain stage(0)

  for (int t = 0; t < NT; t++){
    const int p  = t & 1;
    const int k0 = t * KVB;

    if (t + 1 < NT) STAGE(p ^ 1, t + 1)  // overlaps QKT, drained at B1

    // ---- QK^T: S[qg*32..+32][kgi*16..+16] ----
    f32x4 s0 = (f32x4){0.f,0.f,0.f,0.f}, s1 = s0;
    {
      const u16* kbase = &Klds[p][(kgi*16 + l15) * EMBD];
      const int e7 = l15 & 7;
      #pragma unroll
      for (int es = 0; es < 16; es++){
        const int cst = (es*4 + lg) ^ e7;
        bf16x8 kb = *(const bf16x8*)(kbase + cst*8);
        s0 = __builtin_amdgcn_mfma_f32_16x16x32_bf16(qf[0][es], kb, s0, 0,0,0);
        s1 = __builtin_amdgcn_mfma_f32_16x16x32_bf16(qf[1][es], kb, s1, 0,0,0);
      }
    }
    {
      const int col = kgi*16 + l15, row0 = qg*32 + lg*4;
      #pragma unroll
      for (int rr = 0; rr < 4; rr++){
        Sbuf[row0 + rr][col]      = s0[rr];
        Sbuf[row0 + 16 + rr][col] = s1[rr];
      }
    }

    __syncthreads();                     // B1: Sbuf ready; stage(t+1) drained

    // ---- issue V B-fragments from global Et (consumed after B2) ----
    bf16x8 vbr[2][4];
    {
      const u16* etb = Et + etbase + (size_t)(w*64 + l15) * SEQ + k0 + lg*8;
      #pragma unroll
      for (int jp = 0; jp < 4; jp++){
        const u16* ej = etb + (size_t)jp * 16 * SEQ;
        vbr[0][jp] = *(const bf16x8*)(ej);
        vbr[1][jp] = *(const bf16x8*)(ej + 32);
      }
    }

    // ---- online softmax: thread = (row=tid>>3, cg=tid&7), 8 tok each ----
    {
      const int row = tid >> 3, cg = tid & 7;
      f32x4 sa = *(f32x4*)&Sbuf[row][cg*8];
      f32x4 sb = *(f32x4*)&Sbuf[row][cg*8 + 4];
      float mx = fmaxf(fmaxf(fmaxf(sa[0],sa[1]), fmaxf(sa[2],sa[3])),
                       fmaxf(fmaxf(sb[0],sb[1]), fmaxf(sb[2],sb[3])));
      #pragma unroll
      for (int d = 1; d < 8; d <<= 1) mx = fmaxf(mx, __shfl_xor(mx, d));
      const float mold = m_lds[row], lold = l_lds[row];
      const float mnew = fmaxf(mold, mx);
      float pp[8];
      #pragma unroll
      for (int i = 0; i < 4; i++) pp[i]   = __expf(sa[i] - mnew);
      #pragma unroll
      for (int i = 0; i < 4; i++) pp[4+i] = __expf(sb[i] - mnew);
      float sum = ((pp[0]+pp[1])+(pp[2]+pp[3])) + ((pp[4]+pp[5])+(pp[6]+pp[7]));
      #pragma unroll
      for (int d = 1; d < 8; d <<= 1) sum += __shfl_xor(sum, d);
      const float alpha = __expf(mold - mnew);   // -inf -> 0 on first tile
      if (cg == 0){
        m_lds[row] = mnew;
        l_lds[row] = lold * alpha + sum;
        a_lds[row] = alpha;
      }
      bf16x8 pv;
      #pragma unroll
      for (int i = 0; i < 8; i++) pv[i] = (short)f2bf(pp[i]);
      *(bf16x8*)&Ps[row][cg*8] = pv;
    }

    __syncthreads();                     // B2: Ps + alpha ready

    // ---- rescale O once, then O += P V on wave's 64-column e-slice ----
    #pragma unroll
    for (int ip = 0; ip < 4; ip++){
      f32x4 al = *(f32x4*)&a_lds[ip*16 + lg*4];
      #pragma unroll
      for (int jp = 0; jp < 4; jp++)
        #pragma unroll
        for (int rr = 0; rr < 4; rr++) acc[ip][jp][rr] *= al[rr];
    }
    #pragma unroll
    for (int kt = 0; kt < 2; kt++){
      bf16x8 pa[4];
      #pragma unroll
      for (int ip = 0; ip < 4; ip++)
        pa[ip] = *(const bf16x8*)&Ps[ip*16 + l15][kt*32 + lg*8];
      #pragma unroll
      for (int ip = 0; ip < 4; ip++)
        #pragma unroll
        for (int jp = 0; jp < 4; jp++)
          acc[ip][jp] = __builtin_amdgcn_mfma_f32_16x16x32_bf16(
                            pa[ip], vbr[kt][jp], acc[ip][jp], 0, 0, 0);
    }
  }

  __syncthreads();
  // ---- epilogue: 1/l scaling, column max over 64 q-rows, write partial ----
  #pragma unroll
  for (int ip = 0; ip < 4; ip++){
    f32x4 lv = *(f32x4*)&l_lds[ip*16 + lg*4];
    f32x4 inv;
    #pragma unroll
    for (int rr = 0; rr < 4; rr++) inv[rr] = 1.f / lv[rr];
    #pragma unroll
    for (int jp = 0; jp < 4; jp++)
      #pragma unroll
      for (int rr = 0; rr < 4; rr++) acc[ip][jp][rr] *= inv[rr];
  }
  #pragma unroll
  for (int jp = 0; jp < 4; jp++){
    float cm = -INFINITY;
    #pragma unroll
    for (int ip = 0; ip < 4; ip++)
      #pragma unroll
      for (int rr = 0; rr < 4; rr++) cm = fmaxf(cm, acc[ip][jp][rr]);
    cm = fmaxf(cm, __shfl_xor(cm, 16));
    cm = fmaxf(cm, __shfl_xor(cm, 32));
    if (lg == 0)
      part[(size_t)(b*32 + qt) * EMBD + w*64 + jp*16 + l15] = cm;
  }
}

// ---------------------------------------------------------------------------
// Kernel 1 (fallback, ws too small): R2's proven kernel (Vt in LDS).
// ---------------------------------------------------------------------------
__global__ __launch_bounds__(512, 2) void k_attn_fb(const u16* __restrict__ E,
                                                    float* __restrict__ part){
  __shared__ u16   Klds[KVB * EMBD];
  __shared__ float Sbuf[QB][68];
  __shared__ u16   Ps[QB][72];
  __shared__ u16   Vt[8 * 64 * 64];
  __shared__ float m_lds[QB], l_lds[QB], a_lds[QB];

  const int tid = threadIdx.x;
  const int w   = tid >> 6;
  const int l   = tid & 63;
  const int l15 = l & 15, lg = l >> 4;

  const int blk  = blockIdx.x;
  const int xcd  = blk & 7;
  const int slot = blk >> 3;
  const int b    = xcd + 8 * (slot >> 5);
  const int qt   = slot & 31;
  const size_t ebase = (size_t)b * SEQ * EMBD;

  const int iq = w >> 1, jq = w & 1;
  const u16* qp = E + ebase + (size_t)(qt*QB + iq*16 + l15) * EMBD + lg*8;
  bf16x8 qf[16];
  #pragma unroll
  for (int ks = 0; ks < 16; ks++) qf[ks] = *(const bf16x8*)(qp + ks*32);

  f32x4 acc[4][4];
  #pragma unroll
  for (int ip = 0; ip < 4; ip++)
    #pragma unroll
    for (int jp = 0; jp < 4; jp++) acc[ip][jp] = (f32x4){0.f,0.f,0.f,0.f};

  if (tid < QB){ m_lds[tid] = -INFINITY; l_lds[tid] = 0.f; }

  #pragma unroll
  for (int i = 0; i < 8; i++){
    const int r = w*8 + i;
    const u16* src = E + ebase + (size_t)r * EMBD + ((l ^ (r & 7)) * 8);
    gload_lds16(src, Klds + (size_t)r * EMBD);
  }

  const int quad = l & 15, c8h = l >> 4;

  for (int t = 0; t < NT; t++){
    const int k0 = t * KVB;
    __syncthreads();

    bf16x8 vr[2][4];
    #pragma unroll
    for (int h = 0; h < 2; h++){
      const int c8 = c8h + h*4;
      const u16* vp = E + ebase + (size_t)(k0 + quad*4) * EMBD + w*64 + c8*8;
      vr[h][0] = *(const bf16x8*)(vp);
      vr[h][1] = *(const bf16x8*)(vp +   EMBD);
      vr[h][2] = *(const bf16x8*)(vp + 2*EMBD);
      vr[h][3] = *(const bf16x8*)(vp + 3*EMBD);
    }

    f32x4 s0 = (f32x4){0.f,0.f,0.f,0.f}, s1 = s0;
    const int e7 = l15 & 7;
    const int r0 = jq*32 + l15, r1 = r0 + 16;
    #pragma unroll
    for (int ks = 0; ks < 16; ks++){
      const int c = ks*4 + lg;
      bf16x8 kb0 = *(const bf16x8*)&Klds[(size_t)r0 * EMBD + ((c ^ e7) * 8)];
      bf16x8 kb1 = *(const bf16x8*)&Klds[(size_t)r1 * EMBD + ((c ^ e7) * 8)];
      s0 = __builtin_amdgcn_mfma_f32_16x16x32_bf16(qf[ks], kb0, s0, 0, 0, 0);
      s1 = __builtin_amdgcn_mfma_f32_16x16x32_bf16(qf[ks], kb1, s1, 0, 0, 0);
    }
    #pragma unroll
    for (int rr = 0; rr < 4; rr++){
      Sbuf[iq*16 + lg*4 + rr][jq*32 +      l15] = s0[rr];
      Sbuf[iq*16 + lg*4 + rr][jq*32 + 16 + l15] = s1[rr];
    }

    #pragma unroll
    for (int h = 0; h < 2; h++){
      const int c8 = c8h + h*4;
      #pragma unroll
      for (int i = 0; i < 8; i++){
        const int el = c8*8 + i;
        const int ch = (quad >> 1) ^ (el & 7);
        short4 sv; sv.x = vr[h][0][i]; sv.y = vr[h][1][i];
                   sv.z = vr[h][2][i]; sv.w = vr[h][3][i];
        *(short4*)&Vt[(size_t)w*4096 + el*64 + ch*8 + (quad&1)*4] = sv;
      }
    }

    __syncthreads();

    {
      const int row = tid >> 3, cg = tid & 7;
      f32x4 sa = *(f32x4*)&Sbuf[row][cg*8];
      f32x4 sb = *(f32x4*)&Sbuf[row][cg*8 + 4];
      float mx = fmaxf(fmaxf(fmaxf(sa[0],sa[1]), fmaxf(sa[2],sa[3])),
                       fmaxf(fmaxf(sb[0],sb[1]), fmaxf(sb[2],sb[3])));
      #pragma unroll
      for (int d = 1; d < 8; d <<= 1) mx = fmaxf(mx, __shfl_xor(mx, d));
      const float mold = m_lds[row], lold = l_lds[row];
      const float mnew = fmaxf(mold, mx);
      float pp[8];
      #pragma unroll
      for (int i = 0; i < 4; i++) pp[i]   = __expf(sa[i] - mnew);
      #pragma unroll
      for (int i = 0; i < 4; i++) pp[4+i] = __expf(sb[i] - mnew);
      float sum = ((pp[0]+pp[1])+(pp[2]+pp[3])) + ((pp[4]+pp[5])+(pp[6]+pp[7]));
      #pragma unroll
      for (int d = 1; d < 8; d <<= 1) sum += __shfl_xor(sum, d);
      const float alpha = __expf(mold - mnew);
      if (cg == 0){
        m_lds[row] = mnew;
        l_lds[row] = lold * alpha + sum;
        a_lds[row] = alpha;
      }
      bf16x8 pv;
      #pragma unroll
      for (int i = 0; i < 8; i++) pv[i] = (short)f2bf(pp[i]);
      *(bf16x8*)&Ps[row][cg*8] = pv;
    }

    __syncthreads();

    if (t + 1 < NT){
      #pragma unroll
      for (int i = 0; i < 8; i++){
        const int r = w*8 + i;
        const u16* src = E + ebase + (size_t)(k0 + KVB + r) * EMBD
                           + ((l ^ (r & 7)) * 8);
        gload_lds16(src, Klds + (size_t)r * EMBD);
      }
    }

    #pragma unroll
    for (int ip = 0; ip < 4; ip++){
      f32x4 al = *(f32x4*)&a_lds[ip*16 + lg*4];
      #pragma unroll
      for (int jp = 0; jp < 4; jp++)
        #pragma unroll
        for (int rr = 0; rr < 4; rr++) acc[ip][jp][rr] *= al[rr];
    }
    #pragma unroll
    for (int kt = 0; kt < 2; kt++){
      bf16x8 pa[4], vb[4];
      #pragma unroll
      for (int ip = 0; ip < 4; ip++)
        pa[ip] = *(const bf16x8*)&Ps[ip*16 + l15][kt*32 + lg*8];
      #pragma unroll
      for (int jp = 0; jp < 4; jp++){
        const int el = jp*16 + l15;
        const int ch = (kt*4 + lg) ^ (el & 7);
        vb[jp] = *(const bf16x8*)&Vt[(size_t)w*4096 + el*64 + ch*8];
      }
      #pragma unroll
      for (int ip = 0; ip < 4; ip++)
        #pragma unroll
        for (int jp = 0; jp < 4; jp++)
          acc[ip][jp] = __builtin_amdgcn_mfma_f32_16x16x32_bf16(
                            pa[ip], vb[jp], acc[ip][jp], 0, 0, 0);
    }
  }

  __syncthreads();
  #pragma unroll
  for (int ip = 0; ip < 4; ip++){
    f32x4 lv = *(f32x4*)&l_lds[ip*16 + lg*4];
    f32x4 inv;
    #pragma unroll
    for (int rr = 0; rr < 4; rr++) inv[rr] = 1.f / lv[rr];
    #pragma unroll
    for (int jp = 0; jp < 4; jp++)
      #pragma unroll
      for (int rr = 0; rr < 4; rr++) acc[ip][jp][rr] *= inv[rr];
  }
  #pragma unroll
  for (int jp = 0; jp < 4; jp++){
    float cm = -INFINITY;
    #pragma unroll
    for (int ip = 0; ip < 4; ip++)
      #pragma unroll
      for (int rr = 0; rr < 4; rr++) cm = fmaxf(cm, acc[ip][jp][rr]);
    cm = fmaxf(cm, __shfl_xor(cm, 16));
    cm = fmaxf(cm, __shfl_xor(cm, 32));
    if (lg == 0)
      part[(size_t)(b*32 + qt) * EMBD + w*64 + jp*16 + l15] = cm;
  }
}

// ---------------------------------------------------------------------------
// Kernel 2: pooled[b][e] = max over 32 q-tiles; out[b][o] = pooled.W[o] + b[o]
// ---------------------------------------------------------------------------
__global__ __launch_bounds__(512) void k_final(const float* __restrict__ part,
                                               const float* __restrict__ Wm,
                                               const float* __restrict__ bias,
                                               float* __restrict__ out){
  __shared__ float pooled[EMBD];
  const int b = blockIdx.x, tid = threadIdx.x;
  float mx = -INFINITY;
  const float* pb = part + (size_t)b * 32 * EMBD + tid;
  #pragma unroll
  for (int qt = 0; qt < 32; qt++) mx = fmaxf(mx, pb[qt * EMBD]);
  pooled[tid] = mx;
  __syncthreads();
  const int w = tid >> 6, l = tid & 63;
  float sum = 0.f;
  #pragma unroll
  for (int m = 0; m < 8; m++)
    sum += pooled[l + m*64] * Wm[w*EMBD + l + m*64];
  #pragma unroll
  for (int d = 1; d < 64; d <<= 1) sum += __shfl_xor(sum, d);
  if (l == 0) out[b * NOUT + w] = sum + bias[w];
}

// ---------------------------------------------------------------------------
extern "C" void kernel_launch(void* const* d_in, const int* in_sizes, int n_in,
                              void* d_out, int out_size, void* d_ws, size_t ws_size,
                              hipStream_t stream){
  const int*   x    = (const int*)  d_in[0];   // [16,2048]
  const float* tab  = (const float*)d_in[1];   // [32000,512]
  const float* Wm   = (const float*)d_in[2];   // [8,512]
  const float* bias = (const float*)d_in[3];   // [8]
  float* out = (float*)d_out;                  // [16,8]

  const size_t MB = 1024 * 1024;
  u16* E = (u16*)d_ws;                         // 32 MB

  k_embed<<<BATCH*SEQ/8, 512, 0, stream>>>(x, tab, E);

  if (ws_size >= 66 * MB){
    // ws: E 32MB | Et 32MB | part 1MB
    u16*   Et   = (u16*)((char*)d_ws + 32 * MB);
    float* part = (float*)((char*)d_ws + 64 * MB);
    k_transpose<<<BATCH*32*8, 256, 0, stream>>>(E, Et);
    k_attn_et  <<<BATCH*(SEQ/QB), 512, 0, stream>>>(E, Et, part);
    k_final    <<<BATCH, 512, 0, stream>>>(part, Wm, bias, out);
  } else {
    // ws: E 32MB | part 1MB
    float* part = (float*)((char*)d_ws + 32 * MB);
    k_attn_fb<<<BATCH*(SEQ/QB), 512, 0, stream>>>(E, part);
    k_final  <<<BATCH, 512, 0, stream>>>(part, Wm, bias, out);
  }
}